// Round 14
// baseline (183.855 us; speedup 1.0000x reference)
//
#include <hip/hip_runtime.h>

#define B 64
#define N 1024
#define E 16384
#define NITER 5
#define CSR_SLOTS (E + N)     // even per-node alloc: <=1 pad slot/node, sum<=E+N
#define MAGIC 0xC0FFEE11u

// ---- workspace layout (bytes) ----
// feats 256KB | diag 256B | done 256B. All stored-before-read; done uses a
// MAGIC sentinel so the harness 0xAA poison needs no init (0xAAAAAAAA != MAGIC).
#define FEATS_OFF 0
#define DIAG_OFF  ((size_t)B * N * 4)
#define DONE_OFF  (DIAG_OFF + 256)

// ONE kernel, one block per graph (64 blocks <= 256 CUs => all co-resident,
// so the flag-poll below cannot deadlock):
//   Phase A: edges -> LDS histogram -> scan -> scatter -> in-place O(d^2)
//            dedup (order irrelevant to an integer label sum) -> padded CSR;
//            K = max deduped degree; init label bincount via ballot.
//   Phase B: 5 WL iterations — R12's measured-best rank machinery verbatim
//            (bucketized count + no-tie fast path / tie scan fallback).
//   Phase C: publish feats+diag, __threadfence, done[b]=MAGIC, wave0 polls
//            all 64 flags, then this block computes normalized Gram row b.
__global__ void __launch_bounds__(1024) wl_all_k(const int* __restrict__ src,
                                                 const int* __restrict__ dst,
                                                 const int* __restrict__ lab0,
                                                 const float* __restrict__ hw,
                                                 unsigned int* __restrict__ feats,
                                                 float* __restrict__ diag,
                                                 unsigned int* __restrict__ done,
                                                 float* __restrict__ gout) {
    __shared__ unsigned short s_nbr[CSR_SLOTS];     // 34.8 KB padded CSR
    __shared__ int s_lab[N + 2];                    // +sentinel slot (=0)
    __shared__ int s_hist[N];
    __shared__ int s_scan[N];
    __shared__ float s_grp[N];
    __shared__ int s_flag[N];
    __shared__ unsigned int s_feats[N];
    __shared__ int s_wsum[16];
    __shared__ int s_kp[16];
    __shared__ float s_mn[17], s_mx[17];
    __shared__ int s_K;
    __shared__ int s_anytie;
    int b = blockIdx.x, t = threadIdx.x;
    int lane = t & 63, w = t >> 6;

    // ---- Phase A ----
    const int* sg = src + (size_t)b * E;
    const int* dg = dst + (size_t)b * E;
    int es[16], ed[16];
#pragma unroll
    for (int k = 0; k < 16; ++k) {                  // coalesced, L2-resident
        es[k] = sg[t + k * 1024];
        ed[k] = dg[t + k * 1024];
    }
    int l0 = lab0[(size_t)b * N + t];
    s_lab[t] = l0;
    s_feats[t] = 0;
    s_hist[t] = 0;
    s_flag[t] = 0;
    if (t == 0) { s_lab[N] = 0; s_anytie = 0; }
    __syncthreads();                                        // A0
#pragma unroll
    for (int k = 0; k < 16; ++k) atomicAdd(&s_hist[es[k]], 1);
    __syncthreads();                                        // A1
    int cnt = s_hist[t];                            // with-duplicate count
    int alloc = (cnt + 1) & ~1;                     // even => u32-aligned pairs
    int f = alloc;                                  // wave inclusive scan
#pragma unroll
    for (int d2 = 1; d2 < 64; d2 <<= 1) {
        int v = __shfl_up(f, d2);
        if (lane >= d2) f += v;
    }
    if (lane == 63) s_wsum[w] = f;
    __syncthreads();                                        // A2
    if (t == 0) {                                   // serial exclusive combine
        int run = 0;
#pragma unroll
        for (int k = 0; k < 16; ++k) { int tmp = s_wsum[k]; s_wsum[k] = run; run += tmp; }
    }
    __syncthreads();                                        // A3
    int start = (f - alloc) + s_wsum[w];            // even CSR start
    s_scan[t] = start;                              // scatter cursor
    s_hist[t] = 0;                                  // re-zero for Phase B hist
    __syncthreads();                                        // A4
#pragma unroll
    for (int k = 0; k < 16; ++k) {
        int slot = atomicAdd(&s_scan[es[k]], 1);
        s_nbr[slot] = (unsigned short)ed[k];
    }
    __syncthreads();                                        // A5
    // dedup own segment in place (first-occurrence compaction), pad to alloc
    int dgr = 0;
    for (int k = 0; k < cnt; ++k) {
        unsigned short v = s_nbr[start + k];
        bool dup = false;
        for (int j = 0; j < dgr; ++j)
            if (s_nbr[start + j] == v) { dup = true; break; }
        if (!dup) s_nbr[start + dgr++] = v;
    }
    for (int k = dgr; k < alloc; ++k) s_nbr[start + k] = (unsigned short)N;
    int km = dgr;                                   // K = max deduped degree
#pragma unroll
    for (int o = 32; o > 0; o >>= 1) km = max(km, __shfl_down(km, o));
    if (lane == 0) s_kp[w] = km;
    // init label bincount (labels < 16) via ballot
#pragma unroll
    for (int v = 0; v < 16; ++v) {
        unsigned long long m = __ballot(l0 == v);
        if (lane == v) {
            int c = __popcll(m);
            if (c) atomicAdd(&s_feats[v], (unsigned)c);
        }
    }
    __syncthreads();                                        // A6
    if (t == 0) {
        int m = 0;
#pragma unroll
        for (int k = 0; k < 16; ++k) m = max(m, s_kp[k]);
        s_K = m;
    }
    __syncthreads();                                        // A7
    float Kf = (float)s_K;
    float w0 = hw[0], w1 = hw[1];
    int pairs = alloc >> 1;
    int pstart = start >> 1;

    // ---- Phase B: 5 WL iterations (R12-proven, verbatim) ----
    for (int it = 0; it < NITER; ++it) {
        // seg gather as u32 pairs + exact-_rn hash (bitwise == numpy)
        int s = 0;
        const unsigned int* nbr32 = (const unsigned int*)s_nbr;
        for (int k = 0; k < pairs; ++k) {
            unsigned int pr = nbr32[pstart + k];
            s += s_lab[pr & 0xFFFFu] + s_lab[pr >> 16];
        }
        float t1 = __fmul_rn(__fmul_rn(Kf, w0), (float)s_lab[t]);
        float t2 = __fmul_rn(w1, __fsub_rn(__fadd_rn((float)s, (float)dgr), Kf));
        float h  = __fadd_rn(t1, t2);

        float mn = h, mx = h;
#pragma unroll
        for (int o = 32; o > 0; o >>= 1) {
            mn = fminf(mn, __shfl_down(mn, o));
            mx = fmaxf(mx, __shfl_down(mx, o));
        }
        if (lane == 0) { s_mn[w] = mn; s_mx[w] = mx; }
        __syncthreads();                                    // B1
        if (t == 0) {
            float a = s_mn[0], c = s_mx[0];
#pragma unroll
            for (int k = 1; k < 16; ++k) { a = fminf(a, s_mn[k]); c = fmaxf(c, s_mx[k]); }
            s_mn[16] = a; s_mx[16] = c;
        }
        __syncthreads();                                    // B2
        float fmn = s_mn[16];
        float span = s_mx[16] - fmn;
        float scale = (span > 0.f) ? (1023.0f / span) : 0.f;
        int bucket = min((int)((h - fmn) * scale), 1023);   // order-preserving
        int off_in = atomicAdd(&s_hist[bucket], 1);
        __syncthreads();                                    // B3

        f = s_hist[t];
#pragma unroll
        for (int d2 = 1; d2 < 64; d2 <<= 1) {
            int v = __shfl_up(f, d2);
            if (lane >= d2) f += v;
        }
        if (lane == 63) s_wsum[w] = f;
        __syncthreads();                                    // B4
        if (t == 0) {
            int run = 0;
#pragma unroll
            for (int k = 0; k < 16; ++k) { int tmp = s_wsum[k]; s_wsum[k] = run; run += tmp; }
        }
        __syncthreads();                                    // B5
        s_scan[t] = f + s_wsum[w];
        __syncthreads();                                    // B6

        int bs = s_scan[bucket] - s_hist[bucket];
        int be = s_scan[bucket];
        s_grp[bs + off_in] = h;
        __syncthreads();                                    // B7

        int c = bs;                 // lower buckets strictly less (monotone map)
        int eq = 0;
        for (int k = bs; k < be; ++k) {
            float g = s_grp[k];
            c += (g < h);
            eq += (g == h);
        }
        if (eq > 1) s_anytie = it + 1;  // sentinel: stale iters self-invalidate
        s_hist[t] = 0;                  // re-zero for next iter
        __syncthreads();                                    // B8

        int rank;
        if (s_anytie != it + 1) {
            rank = c;                   // distinct keys: c IS the dense rank
            s_lab[t] = rank;
            s_feats[rank] += 1u;        // permutation -> conflict-free
        } else {
            s_flag[c] = 1;              // class start (same class -> same c)
            __syncthreads();                                // T1
            int f2 = s_flag[t];
#pragma unroll
            for (int d2 = 1; d2 < 64; d2 <<= 1) {
                int v = __shfl_up(f2, d2);
                if (lane >= d2) f2 += v;
            }
            if (lane == 63) s_wsum[w] = f2;
            __syncthreads();                                // T2
            if (t == 0) {
                int run = 0;
#pragma unroll
                for (int k = 0; k < 16; ++k) { int tmp = s_wsum[k]; s_wsum[k] = run; run += tmp; }
            }
            __syncthreads();                                // T3
            s_scan[t] = f2 + s_wsum[w];
            s_flag[t] = 0;              // own flag consumed above
            __syncthreads();                                // T4
            rank = s_scan[c] - 1;
            s_lab[t] = rank;
            atomicAdd(&s_feats[rank], 1u);
        }
        __syncthreads();                                    // B9
    }

    // ---- Phase C: publish + handshake + own Gram row ----
    unsigned int fv = s_feats[t];
    feats[(size_t)b * N + t] = fv;
    int sq = (int)(fv * fv);
#pragma unroll
    for (int o = 32; o > 0; o >>= 1) sq += __shfl_down(sq, o);
    if (lane == 0) s_kp[w] = sq;
    __syncthreads();
    if (t == 0) {
        int tot = 0;
#pragma unroll
        for (int k = 0; k < 16; ++k) tot += s_kp[k];
        diag[b] = (float)tot;           // exact: trailing-zero-rich ints
    }
    __threadfence();                    // drain feats+diag to device scope
    if (t == 0) atomicExch(&done[b], MAGIC);
    if (w == 0) {                       // wave0 lane i polls done[i]
        unsigned int v;
        do { v = atomicAdd(&done[lane], 0u); } while (__ballot(v != MAGIC));
    }
    __syncthreads();
    __threadfence();                    // acquire side

    float db = diag[b];
#pragma unroll
    for (int jj = 0; jj < 4; ++jj) {
        int j = w * 4 + jj;             // 16 waves x 4 = all 64 columns
        const uint4* fj = (const uint4*)(feats + (size_t)j * N);
        const uint4* fi = (const uint4*)s_feats;
        int s = 0;
#pragma unroll
        for (int k = 0; k < 4; ++k) {
            uint4 vb = fj[lane + k * 64];
            uint4 va = fi[lane + k * 64];
            s += (int)(va.x * vb.x) + (int)(va.y * vb.y)
               + (int)(va.z * vb.z) + (int)(va.w * vb.w);
        }
#pragma unroll
        for (int o = 32; o > 0; o >>= 1) s += __shfl_down(s, o);
        if (lane == 0) gout[b * B + j] = (float)s / sqrtf(db * diag[j]);
    }
}

extern "C" void kernel_launch(void* const* d_in, const int* in_sizes, int n_in,
                              void* d_out, int out_size, void* d_ws, size_t ws_size,
                              hipStream_t stream) {
    const int*   esrc = (const int*)d_in[0];
    const int*   edst = (const int*)d_in[1];
    const int*   lab0 = (const int*)d_in[2];
    const float* hw   = (const float*)d_in[3];

    char* ws = (char*)d_ws;
    unsigned int* feats = (unsigned int*)(ws + FEATS_OFF);
    float*        diag  = (float*)(ws + DIAG_OFF);
    unsigned int* done  = (unsigned int*)(ws + DONE_OFF);

    wl_all_k<<<B, 1024, 0, stream>>>(esrc, edst, lab0, hw, feats, diag, done,
                                     (float*)d_out);
}

// Round 15
// 143.416 us; speedup vs baseline: 1.2820x; 1.2820x over previous
//
#include <hip/hip_runtime.h>

#define B 64
#define N 1024
#define E 16384
#define WPR 32          // words per adjacency row = N/32
#define NITER 5
#define CSR_SLOTS (E + N)   // even-aligned per-node alloc: <=1 pad slot/node
#define MAGIC 0xC0FFEE11u

// ---- workspace layout (bytes) ---- (NO memset: every region fully stored
// before any read; done[] uses a MAGIC sentinel, 0xAA poison != MAGIC)
#define ADJ_OFF   0
#define ADJ_BYTES ((size_t)B * N * WPR * 4)
#define FEATS_OFF ADJ_BYTES
#define DIAG_OFF  (FEATS_OFF + (size_t)B * N * 4)
#define DONE_OFF  (DIAG_OFF + 256)

// Bit adjacency built in LDS, full rows STORED to global. R14 proved the
// bitmask is load-bearing: its atomicOr dedup is parallel+free, whereas the
// in-block CSR histogram/scatter/O(d^2)-dedup cost ~85us and 1.87M conflicts.
__global__ void __launch_bounds__(1024) build_adj_k(const int* __restrict__ src,
                                                    const int* __restrict__ dst,
                                                    unsigned int* __restrict__ adj) {
    __shared__ unsigned int s_adj[512 * WPR];       // 64 KiB: 512 rows
    int t = threadIdx.x;
    int b = blockIdx.x >> 1;
    int half = blockIdx.x & 1;
    int row_base = half << 9;

    uint4* s4 = (uint4*)s_adj;
#pragma unroll
    for (int k = 0; k < 4; ++k) s4[t + k * 1024] = make_uint4(0, 0, 0, 0);
    __syncthreads();

    const int* sg = src + (size_t)b * E;
    const int* dg = dst + (size_t)b * E;
#pragma unroll
    for (int k = 0; k < 16; ++k) {
        int e = t + k * 1024;
        int s = sg[e];
        int d = dg[e];
        int r = s - row_base;
        if ((unsigned)r < 512u)
            atomicOr(&s_adj[r * WPR + (d >> 5)], 1u << (d & 31));  // idempotent dedup
    }
    __syncthreads();

    uint4* g4 = (uint4*)(adj + ((size_t)b * N + row_base) * WPR);
#pragma unroll
    for (int k = 0; k < 4; ++k) g4[t + k * 1024] = s4[t + k * 1024];
}

// One block per graph: R12's proven Phase A (bitmask -> packed CSR) and
// Phase B (bucketized rank, no-tie fast path) verbatim; Phase C fuses the
// Gram row via device-scope MAGIC handshake (validated correct in R14).
__global__ void __launch_bounds__(1024) wl_mega_k(const unsigned int* __restrict__ adj,
                                                  const int* __restrict__ lab0,
                                                  const float* __restrict__ hw,
                                                  unsigned int* __restrict__ feats,
                                                  float* __restrict__ diag,
                                                  unsigned int* __restrict__ done,
                                                  float* __restrict__ gout) {
    __shared__ unsigned short s_nbr[CSR_SLOTS];     // 34 KB even-aligned CSR
    __shared__ int s_lab[N + 2];                    // +sentinel slot (=0)
    __shared__ int s_hist[N];
    __shared__ int s_scan[N];
    __shared__ float s_grp[N];
    __shared__ int s_flag[N];
    __shared__ unsigned int s_feats[N];
    __shared__ int s_wsum[16];
    __shared__ float s_mn[17], s_mx[17];
    __shared__ int s_K;
    __shared__ int s_anytie;
    int b = blockIdx.x, t = threadIdx.x;
    int lane = t & 63, w = t >> 6;

    // ---- Phase A: row -> deg/CSR/K, init labels + bincount ----
    uint4 r[8];
    const uint4* rowg = (const uint4*)(adj + ((size_t)b * N + t) * WPR);
#pragma unroll
    for (int k = 0; k < 8; ++k) r[k] = rowg[k];
    int dg = 0;
#pragma unroll
    for (int k = 0; k < 8; ++k)
        dg += __popc(r[k].x) + __popc(r[k].y) + __popc(r[k].z) + __popc(r[k].w);
    int alloc = (dg + 1) & ~1;                      // even per-node CSR alloc

    int f = alloc;                                  // wave scan of alloc
#pragma unroll
    for (int d2 = 1; d2 < 64; d2 <<= 1) {
        int v = __shfl_up(f, d2);
        if (lane >= d2) f += v;
    }
    int km = dg;
#pragma unroll
    for (int o = 32; o > 0; o >>= 1) km = max(km, __shfl_down(km, o));
    if (lane == 63) s_wsum[w] = f;
    if (lane == 0)  s_scan[w] = km;                 // scratch for K partials

    int l0 = lab0[(size_t)b * N + t];
    s_lab[t] = l0;
    s_feats[t] = 0;
    s_hist[t] = 0;
    s_flag[t] = 0;
    if (t == 0) { s_lab[N] = 0; s_anytie = 0; }
    __syncthreads();                                        // A1
    if (t == 0) {                                   // serial combine (R7-style)
        int run = 0, m = 0;
#pragma unroll
        for (int k = 0; k < 16; ++k) {
            int tmp = s_wsum[k]; s_wsum[k] = run; run += tmp;
            m = max(m, s_scan[k]);
        }
        s_K = m;
    }
    // init label bincount (labels < 16) via ballot
#pragma unroll
    for (int v = 0; v < 16; ++v) {
        unsigned long long m = __ballot(l0 == v);
        if (lane == v) {
            int c = __popcll(m);
            if (c) atomicAdd(&s_feats[v], (unsigned)c);
        }
    }
    __syncthreads();                                        // A2
    int start = (f - alloc) + s_wsum[w];            // even => u32-aligned

    // pack own row's set bits ONCE -> u16 list; pad odd deg with sentinel N
    {
        int idx = start;
#pragma unroll
        for (int k = 0; k < 8; ++k) {
            unsigned int wv[4] = { r[k].x, r[k].y, r[k].z, r[k].w };
#pragma unroll
            for (int c2 = 0; c2 < 4; ++c2) {
                unsigned int word = wv[c2];
                int bb = (k * 4 + c2) << 5;
                while (word) {
                    int j = __ffs(word) - 1;
                    word &= word - 1;
                    s_nbr[idx++] = (unsigned short)(bb + j);
                }
            }
        }
        if (dg & 1) s_nbr[idx] = (unsigned short)N; // sentinel -> adds 0
    }
    float Kf = (float)s_K;
    float w0 = hw[0], w1 = hw[1];
    int pairs = alloc >> 1;
    int pstart = start >> 1;
    __syncthreads();                                        // A3

    // ---- Phase B: 5 WL iterations (R12-proven, verbatim) ----
    for (int it = 0; it < NITER; ++it) {
        int s = 0;
        const unsigned int* nbr32 = (const unsigned int*)s_nbr;
        for (int k = 0; k < pairs; ++k) {
            unsigned int pr = nbr32[pstart + k];
            s += s_lab[pr & 0xFFFFu] + s_lab[pr >> 16];
        }
        float t1 = __fmul_rn(__fmul_rn(Kf, w0), (float)s_lab[t]);
        float t2 = __fmul_rn(w1, __fsub_rn(__fadd_rn((float)s, (float)dg), Kf));
        float h  = __fadd_rn(t1, t2);

        float mn = h, mx = h;
#pragma unroll
        for (int o = 32; o > 0; o >>= 1) {
            mn = fminf(mn, __shfl_down(mn, o));
            mx = fmaxf(mx, __shfl_down(mx, o));
        }
        if (lane == 0) { s_mn[w] = mn; s_mx[w] = mx; }
        __syncthreads();                                    // B1
        if (t == 0) {
            float a = s_mn[0], c = s_mx[0];
#pragma unroll
            for (int k = 1; k < 16; ++k) { a = fminf(a, s_mn[k]); c = fmaxf(c, s_mx[k]); }
            s_mn[16] = a; s_mx[16] = c;
        }
        __syncthreads();                                    // B2
        float fmn = s_mn[16];
        float span = s_mx[16] - fmn;
        float scale = (span > 0.f) ? (1023.0f / span) : 0.f;
        int bucket = min((int)((h - fmn) * scale), 1023);   // order-preserving
        int off_in = atomicAdd(&s_hist[bucket], 1);
        __syncthreads();                                    // B3

        f = s_hist[t];
#pragma unroll
        for (int d2 = 1; d2 < 64; d2 <<= 1) {
            int v = __shfl_up(f, d2);
            if (lane >= d2) f += v;
        }
        if (lane == 63) s_wsum[w] = f;
        __syncthreads();                                    // B4
        if (t == 0) {
            int run = 0;
#pragma unroll
            for (int k = 0; k < 16; ++k) { int tmp = s_wsum[k]; s_wsum[k] = run; run += tmp; }
        }
        __syncthreads();                                    // B5
        s_scan[t] = f + s_wsum[w];
        __syncthreads();                                    // B6

        int bs = s_scan[bucket] - s_hist[bucket];
        int be = s_scan[bucket];
        s_grp[bs + off_in] = h;
        __syncthreads();                                    // B7

        int c = bs;                 // lower buckets strictly less (monotone map)
        int eq = 0;
        for (int k = bs; k < be; ++k) {
            float g = s_grp[k];
            c += (g < h);
            eq += (g == h);
        }
        if (eq > 1) s_anytie = it + 1;  // sentinel: stale iters self-invalidate
        s_hist[t] = 0;                  // re-zero for next iter
        __syncthreads();                                    // B8

        int rank;
        if (s_anytie != it + 1) {
            rank = c;                   // distinct keys: c IS the dense rank
            s_lab[t] = rank;
            s_feats[rank] += 1u;        // permutation -> conflict-free
        } else {
            s_flag[c] = 1;              // class start (same class -> same c)
            __syncthreads();                                // T1
            int f2 = s_flag[t];
#pragma unroll
            for (int d2 = 1; d2 < 64; d2 <<= 1) {
                int v = __shfl_up(f2, d2);
                if (lane >= d2) f2 += v;
            }
            if (lane == 63) s_wsum[w] = f2;
            __syncthreads();                                // T2
            if (t == 0) {
                int run = 0;
#pragma unroll
                for (int k = 0; k < 16; ++k) { int tmp = s_wsum[k]; s_wsum[k] = run; run += tmp; }
            }
            __syncthreads();                                // T3
            s_scan[t] = f2 + s_wsum[w];
            s_flag[t] = 0;              // own flag consumed above
            __syncthreads();                                // T4
            rank = s_scan[c] - 1;
            s_lab[t] = rank;
            atomicAdd(&s_feats[rank], 1u);
        }
        __syncthreads();                                    // B9
    }

    // ---- Phase C: publish + handshake + own Gram row (R14-validated) ----
    unsigned int fv = s_feats[t];
    feats[(size_t)b * N + t] = fv;
    int sq = (int)(fv * fv);
#pragma unroll
    for (int o = 32; o > 0; o >>= 1) sq += __shfl_down(sq, o);
    if (lane == 0) s_wsum[w] = sq;
    __syncthreads();
    if (t == 0) {
        int tot = 0;
#pragma unroll
        for (int k = 0; k < 16; ++k) tot += s_wsum[k];
        diag[b] = (float)tot;           // int-exact
    }
    __threadfence();                    // drain feats+diag to device scope
    if (t == 0) atomicExch(&done[b], MAGIC);
    if (w == 0) {                       // wave0 lane i polls done[i]
        unsigned int v;
        do { v = atomicAdd(&done[lane], 0u); } while (__ballot(v != MAGIC));
    }
    __syncthreads();
    __threadfence();                    // acquire side

    float db = diag[b];
#pragma unroll
    for (int jj = 0; jj < 4; ++jj) {
        int j = w * 4 + jj;             // 16 waves x 4 = all 64 columns
        const uint4* fj = (const uint4*)(feats + (size_t)j * N);
        const uint4* fi = (const uint4*)s_feats;
        int s = 0;
#pragma unroll
        for (int k = 0; k < 4; ++k) {
            uint4 vb = fj[lane + k * 64];
            uint4 va = fi[lane + k * 64];
            s += (int)(va.x * vb.x) + (int)(va.y * vb.y)
               + (int)(va.z * vb.z) + (int)(va.w * vb.w);
        }
#pragma unroll
        for (int o = 32; o > 0; o >>= 1) s += __shfl_down(s, o);
        if (lane == 0) gout[b * B + j] = (float)s / sqrtf(db * diag[j]);
    }
}

extern "C" void kernel_launch(void* const* d_in, const int* in_sizes, int n_in,
                              void* d_out, int out_size, void* d_ws, size_t ws_size,
                              hipStream_t stream) {
    const int*   esrc = (const int*)d_in[0];
    const int*   edst = (const int*)d_in[1];
    const int*   lab0 = (const int*)d_in[2];
    const float* hw   = (const float*)d_in[3];

    char* ws = (char*)d_ws;
    unsigned int* adj   = (unsigned int*)(ws + ADJ_OFF);
    unsigned int* feats = (unsigned int*)(ws + FEATS_OFF);
    float*        diag  = (float*)(ws + DIAG_OFF);
    unsigned int* done  = (unsigned int*)(ws + DONE_OFF);

    build_adj_k<<<B * 2, 1024, 0, stream>>>(esrc, edst, adj);
    wl_mega_k<<<B, 1024, 0, stream>>>(adj, lab0, hw, feats, diag, done,
                                      (float*)d_out);
}